// Round 13
// baseline (1255.951 us; speedup 1.0000x reference)
//
#include <hip/hip_runtime.h>
#include <hip/hip_fp16.h>
#include <math.h>

typedef _Float16 h16;
typedef __attribute__((ext_vector_type(8))) _Float16 half8;
typedef __attribute__((ext_vector_type(4))) float f32x4;

#define GLOAD_LDS16(gp, lp) __builtin_amdgcn_global_load_lds( \
    (const __attribute__((address_space(1))) void*)(gp),      \
    (__attribute__((address_space(3))) void*)(lp), 16, 0, 0)

// ---- GEMM core: B via LDS (3-buffer, swizzled), A via REGISTERS ------------
// A-fragments are per-lane 16B global loads from L2-hot h (1 MB) -> no LDS
// round-trip, no barrier dependency for A. 3-deep static register rotation
// (loop fully unrolled -> compile-time indices, rule #20). B keeps the proven
// gload_lds + XOR-swizzle + two-barrier schedule. Per staged tile: 6 vm
// events (4 B-gloads then 2 A-loads); depth-2 -> steady vmcnt(12) retires
// exactly tile kk's 6 (in-order, m135). Fragment values and MFMA order are
// bit-identical to the round-5 kernel.
union SmemGemm {
  h16   buf[3][64 * 128];   // 3 x 16KB B staging (64 rows x 128 k)
  float red[4][2048];       // 32KB cross-wave reduction, aliased
};

__device__ __forceinline__ void stageB3(SmemGemm& sm, int bi,
                                        const h16* __restrict__ Bg,
                                        int kk, int kdim, int wave, int lane) {
  h16* Bs = sm.buf[bi];
  const int kb = kk * 128;
  // B tile: 64 rows x 128 k = 1024 granules of 16B, 4 insts/wave
#pragma unroll
  for (int i = 0; i < 4; ++i) {
    const int id = wave * 4 + i;              // 0..15
    const int chunk = id * 64 + lane;         // 0..1023
    const int r = chunk >> 4, cg = chunk & 15;
    GLOAD_LDS16(Bg + (long)r * kdim + kb + ((cg ^ (r & 7)) << 3),
                Bs + id * 512);
  }
}

// C[i,j] partials in sm.red[wave][i*64+j]; caller sums the 4 waves.
// Wave w covers k-window [w*32, w*32+32) of each BK=128 slab.
template <int KDIM>
__device__ __forceinline__ void gemm_core(SmemGemm& sm,
                                          const h16* __restrict__ Ag,
                                          const h16* __restrict__ Bg,
                                          int wave, int lane) {
  f32x4 acc[2][4];
#pragma unroll
  for (int a = 0; a < 2; ++a)
#pragma unroll
    for (int c = 0; c < 4; ++c) acc[a][c] = (f32x4){0.f, 0.f, 0.f, 0.f};

  const int mr = lane & 15, q = lane >> 4;
  const int kg = wave * 4 + q;                // k-granule 0..15
  const int ro = ((kg ^ (mr & 7)) << 3);      // swizzled B elem offset in row
  const h16* aRow0 = Ag + (long)mr * KDIM + kg * 8;         // A row mr
  const h16* aRow1 = Ag + (long)(mr + 16) * KDIM + kg * 8;  // A row mr+16
  constexpr int NIT = KDIM / 128;
  half8 a0r[3], a1r[3];

  // prologue: tiles 0,1 (B-gloads then A-reg loads per tile -> 6 events each)
  stageB3(sm, 0, Bg, 0, KDIM, wave, lane);
  a0r[0] = *(const half8*)(aRow0);
  a1r[0] = *(const half8*)(aRow1);
  stageB3(sm, 1, Bg, 1, KDIM, wave, lane);
  a0r[1] = *(const half8*)(aRow0 + 128);
  a1r[1] = *(const half8*)(aRow1 + 128);
#pragma unroll
  for (int kk = 0; kk < NIT; ++kk) {
    if (kk + 2 < NIT) {
      stageB3(sm, (kk + 2) % 3, Bg, kk + 2, KDIM, wave, lane);
      a0r[(kk + 2) % 3] = *(const half8*)(aRow0 + (kk + 2) * 128);
      a1r[(kk + 2) % 3] = *(const half8*)(aRow1 + (kk + 2) * 128);
      asm volatile("s_waitcnt vmcnt(12)" ::: "memory");  // tile kk's 6 done
    } else if (kk + 2 == NIT) {
      asm volatile("s_waitcnt vmcnt(6)" ::: "memory");
    } else {
      asm volatile("s_waitcnt vmcnt(0)" ::: "memory");
    }
    __builtin_amdgcn_s_barrier();             // ALL waves' B tile kk in LDS
    const h16* Bs = sm.buf[kk % 3];
#pragma unroll
    for (int fc = 0; fc < 4; ++fc) {
      half8 bv = *(const half8*)(Bs + (fc * 16 + mr) * 128 + ro);
      acc[0][fc] = __builtin_amdgcn_mfma_f32_16x16x32_f16(a0r[kk % 3], bv, acc[0][fc], 0, 0, 0);
      acc[1][fc] = __builtin_amdgcn_mfma_f32_16x16x32_f16(a1r[kk % 3], bv, acc[1][fc], 0, 0, 0);
    }
    asm volatile("s_waitcnt lgkmcnt(0)" ::: "memory");   // my B reads done
    __builtin_amdgcn_s_barrier();             // all waves' reads done
  }
  __syncthreads();                            // red aliases staging
#pragma unroll
  for (int fr = 0; fr < 2; ++fr)
#pragma unroll
    for (int fc = 0; fc < 4; ++fc)
#pragma unroll
      for (int r = 0; r < 4; ++r)
        sm.red[wave][(fr * 16 + q * 4 + r) * 64 + fc * 16 + mr] = acc[fr][fc][r];
  __syncthreads();
}

__device__ __forceinline__ float fast_tanh(float x) {
  float e = __expf(2.0f * fabsf(x));          // saturates safely for |x| large
  float t = 1.0f - 2.0f / (e + 1.0f);
  return copysignf(t, x);
}

// ---- pre-pass: sigma = ||W t|| / ||t||, t = W^T u --------------------------
__global__ void k_zero(float* tbuf, float* sbuf) {
  const int t = threadIdx.x;
  tbuf[t] = 0.f;
  if (t < 2) sbuf[t] = 0.f;
}

__global__ void __launch_bounds__(256)
k_prep1(const float* __restrict__ Win, const float* __restrict__ u,
        float* __restrict__ t) {
  const int kc = blockIdx.x & 3, jc = blockIdx.x >> 2;
  const int k = kc * 256 + threadIdx.x;       // coalesced
  const int j0 = jc * 64;
  float acc = 0.f;
#pragma unroll 4
  for (int j = 0; j < 64; ++j)
    acc = fmaf(Win[(long)(j0 + j) * 1024 + k], u[j0 + j], acc);
  atomicAdd(&t[k], acc);
}

__global__ void __launch_bounds__(256)
k_prep1b(const float* __restrict__ t, float* __restrict__ sbuf) {
  const int k = blockIdx.x * 256 + threadIdx.x;
  float v = t[k];
  float p = v * v;
#pragma unroll
  for (int off = 32; off > 0; off >>= 1) p += __shfl_down(p, off);
  if ((threadIdx.x & 63) == 0) atomicAdd(&sbuf[0], p);     // s1 = ||t||^2
}

__global__ void __launch_bounds__(256)
k_prep2(const float* __restrict__ Win, const float* __restrict__ t,
        float* __restrict__ sbuf) {
  const int row = blockIdx.x * 4 + (threadIdx.x >> 6);
  const int lane = threadIdx.x & 63;
  float acc = 0.f;
  for (int kk = lane; kk < 1024; kk += 64)
    acc = fmaf(Win[row * 1024 + kk], t[kk], acc);
#pragma unroll
  for (int off = 32; off > 0; off >>= 1) acc += __shfl_down(acc, off);
  if (lane == 0) atomicAdd(&sbuf[1], acc * acc);           // s2 = ||W t||^2
}

// ---- fp32 -> fp16 conversions (one fused elementwise pass) -----------------
__global__ void __launch_bounds__(256)
k_cvt(const float* __restrict__ W0, const float* __restrict__ W1,
      const float* __restrict__ W2, const float* __restrict__ Win,
      const float* __restrict__ Hw, const float* __restrict__ X,
      h16* __restrict__ w16, h16* __restrict__ wi16,
      h16* __restrict__ hw16, h16* __restrict__ x16) {
  const long e = (long)(blockIdx.x * 256 + threadIdx.x) * 8;
  const float* src; h16* dst;
  if (e < 4194304)       { src = W0 + e;              dst = w16 + e; }
  else if (e < 8388608)  { src = W1 + (e - 4194304);  dst = w16 + e; }
  else if (e < 12582912) { src = W2 + (e - 8388608);  dst = w16 + e; }
  else if (e < 14680064) { src = Win + (e - 12582912); dst = wi16 + (e - 12582912); }
  else if (e < 16728064) { src = Hw + (e - 14680064);  dst = hw16 + (e - 14680064); }
  else if (e < 16777216) {                              // zero-pad head_w rows 1000..1023
    half8 z = (half8){};
    *(half8*)(hw16 + 2048000 + (e - 16728064)) = z;
    return;
  }
  else                   { src = X + (e - 16777216);   dst = x16 + (e - 16777216); }
  f32x4 f0 = *(const f32x4*)src, f1 = *(const f32x4*)(src + 4);
  half8 h;
#pragma unroll
  for (int i = 0; i < 4; ++i) { h[i] = (h16)f0[i]; h[i + 4] = (h16)f1[i]; }
  *(half8*)dst = h;
}

// ---- x_proj = (x @ Win^T)/sigma + Win_b; zero h32/h16a ---------------------
__global__ void __launch_bounds__(256)
k_xproj(const h16* __restrict__ x16, const h16* __restrict__ wi16,
        const float* __restrict__ Winb, const float* __restrict__ sbuf,
        float* __restrict__ xp, float* __restrict__ h32, h16* __restrict__ h16a) {
  __shared__ SmemGemm sm;
  const int rb = blockIdx.x >> 5, cb = blockIdx.x & 31;
  const int wave = threadIdx.x >> 6, lane = threadIdx.x & 63;
  gemm_core<1024>(sm, x16 + rb * 32 * 1024, wi16 + (long)cb * 64 * 1024, wave, lane);
  const float inv_sigma = sqrtf(sbuf[0] / sbuf[1]);        // ||t|| / ||W t||
  const int e = threadIdx.x * 8;
  const int gi = rb * 32 + (e >> 6), gj = cb * 64 + (e & 63);
  const long base = (long)gi * 2048 + gj;
  f32x4 s0 = *(const f32x4*)&sm.red[0][e], s1 = *(const f32x4*)&sm.red[0][e + 4];
#pragma unroll
  for (int w = 1; w < 4; ++w) {
    s0 += *(const f32x4*)&sm.red[w][e];
    s1 += *(const f32x4*)&sm.red[w][e + 4];
  }
  f32x4 b0v = *(const f32x4*)&Winb[gj], b1v = *(const f32x4*)&Winb[gj + 4];
  f32x4 v0 = s0 * inv_sigma + b0v, v1 = s1 * inv_sigma + b1v;
  *(f32x4*)&xp[base] = v0; *(f32x4*)&xp[base + 4] = v1;
  f32x4 zz = (f32x4){0.f, 0.f, 0.f, 0.f};
  *(f32x4*)&h32[base] = zz; *(f32x4*)&h32[base + 4] = zz;
  half8 hz = (half8){};
  *(half8*)&h16a[base] = hz;
}

// ---- one layer: h = 0.5h + 0.5 tanh(xp + h W^T + b) ------------------------
__global__ void __launch_bounds__(256)
k_layer(const h16* __restrict__ hin, const h16* __restrict__ W,
        const float* __restrict__ bl, const float* __restrict__ xp,
        float* __restrict__ h32, h16* __restrict__ hout) {
  __shared__ SmemGemm sm;
  const int rb = blockIdx.x >> 5, cb = blockIdx.x & 31;  // cb%8==blk%8: XCD-pinned cols
  const int wave = threadIdx.x >> 6, lane = threadIdx.x & 63;
  gemm_core<2048>(sm, hin + rb * 32 * 2048, W + (long)cb * 64 * 2048, wave, lane);
  const int e = threadIdx.x * 8;
  const int gi = rb * 32 + (e >> 6), gj = cb * 64 + (e & 63);
  const long base = (long)gi * 2048 + gj;
  f32x4 s0 = *(const f32x4*)&sm.red[0][e], s1 = *(const f32x4*)&sm.red[0][e + 4];
#pragma unroll
  for (int w = 1; w < 4; ++w) {
    s0 += *(const f32x4*)&sm.red[w][e];
    s1 += *(const f32x4*)&sm.red[w][e + 4];
  }
  f32x4 xp0 = *(const f32x4*)&xp[base], xp1 = *(const f32x4*)&xp[base + 4];
  f32x4 b0v = *(const f32x4*)&bl[gj],   b1v = *(const f32x4*)&bl[gj + 4];
  f32x4 ho0 = *(const f32x4*)&h32[base], ho1 = *(const f32x4*)&h32[base + 4];
  f32x4 z0 = xp0 + s0 + b0v, z1 = xp1 + s1 + b1v;
  f32x4 hn0, hn1; half8 hh;
#pragma unroll
  for (int i = 0; i < 4; ++i) {
    hn0[i] = 0.5f * ho0[i] + 0.5f * fast_tanh(z0[i]);
    hn1[i] = 0.5f * ho1[i] + 0.5f * fast_tanh(z1[i]);
    hh[i] = (h16)hn0[i]; hh[i + 4] = (h16)hn1[i];
  }
  *(f32x4*)&h32[base] = hn0; *(f32x4*)&h32[base + 4] = hn1;
  *(half8*)&hout[base] = hh;
}

// ---- head: out = h @ head_w^T + head_b -------------------------------------
__global__ void __launch_bounds__(256)
k_head(const h16* __restrict__ hf, const h16* __restrict__ hw16,
       const float* __restrict__ hb, float* __restrict__ out) {
  __shared__ SmemGemm sm;
  const int rb = blockIdx.x >> 4, cb = blockIdx.x & 15;
  const int wave = threadIdx.x >> 6, lane = threadIdx.x & 63;
  gemm_core<2048>(sm, hf + rb * 32 * 2048, hw16 + (long)cb * 64 * 2048, wave, lane);
  const int e = threadIdx.x * 8;
  const int gi = rb * 32 + (e >> 6), gj = cb * 64 + (e & 63);
  f32x4 s0 = *(const f32x4*)&sm.red[0][e], s1 = *(const f32x4*)&sm.red[0][e + 4];
#pragma unroll
  for (int w = 1; w < 4; ++w) {
    s0 += *(const f32x4*)&sm.red[w][e];
    s1 += *(const f32x4*)&sm.red[w][e + 4];
  }
#pragma unroll
  for (int i = 0; i < 4; ++i) {
    int j0 = gj + i;
    if (j0 < 1000) out[(long)gi * 1000 + j0] = s0[i] + hb[j0];
    int j1 = gj + 4 + i;
    if (j1 < 1000) out[(long)gi * 1000 + j1] = s1[i] + hb[j1];
  }
}

// ---- workspace layout (bytes) ----------------------------------------------
#define OFF_W16   0L          // 3 x 2048x2048 fp16 = 25165824
#define OFF_WI16  25165824L   // 2048x1024 fp16     =  4194304
#define OFF_X16   29360128L   // 256x1024 fp16      =   524288
#define OFF_HW16  29884416L   // 1024x2048 fp16     =  4194304 (padded rows)
#define OFF_XP    34078720L   // 256x2048 fp32      =  2097152
#define OFF_H32   36175872L   // 256x2048 fp32      =  2097152
#define OFF_H16A  38273024L   // 256x2048 fp16      =  1048576
#define OFF_H16B  39321600L   //                    =  1048576
#define OFF_T     40370176L   // 1024 fp32
#define OFF_S     40374272L   // s1, s2

extern "C" void kernel_launch(void* const* d_in, const int* in_sizes, int n_in,
                              void* d_out, int out_size, void* d_ws, size_t ws_size,
                              hipStream_t stream) {
  const float* x     = (const float*)d_in[0];
  const float* Win_w = (const float*)d_in[1];
  const float* Win_b = (const float*)d_in[2];
  const float* u     = (const float*)d_in[3];
  const float* W0    = (const float*)d_in[4];
  const float* b0    = (const float*)d_in[5];
  const float* W1    = (const float*)d_in[6];
  const float* b1    = (const float*)d_in[7];
  const float* W2    = (const float*)d_in[8];
  const float* b2    = (const float*)d_in[9];
  const float* headw = (const float*)d_in[10];
  const float* headb = (const float*)d_in[11];

  char* ws = (char*)d_ws;
  h16*   w16  = (h16*)(ws + OFF_W16);
  h16*   wi16 = (h16*)(ws + OFF_WI16);
  h16*   x16  = (h16*)(ws + OFF_X16);
  h16*   hw16 = (h16*)(ws + OFF_HW16);
  float* xp   = (float*)(ws + OFF_XP);
  float* h32  = (float*)(ws + OFF_H32);
  h16*   h16a = (h16*)(ws + OFF_H16A);
  h16*   h16b = (h16*)(ws + OFF_H16B);
  float* tbuf = (float*)(ws + OFF_T);
  float* sbuf = (float*)(ws + OFF_S);

  k_zero<<<1, 1024, 0, stream>>>(tbuf, sbuf);
  k_prep1<<<128, 256, 0, stream>>>(Win_w, u, tbuf);
  k_prep1b<<<4, 256, 0, stream>>>(tbuf, sbuf);
  k_prep2<<<512, 256, 0, stream>>>(Win_w, tbuf, sbuf);
  k_cvt<<<8320, 256, 0, stream>>>(W0, W1, W2, Win_w, headw, x, w16, wi16, hw16, x16);
  k_xproj<<<256, 256, 0, stream>>>(x16, wi16, Win_b, sbuf, xp, h32, h16a);

  const h16*   wptr[3] = {w16, w16 + 4194304, w16 + 8388608};
  const float* bptr[3] = {b0, b1, b2};
  h16* hbuf[2] = {h16a, h16b};
  for (int s = 0; s < 30; ++s) {
    for (int l = 0; l < 3; ++l) {
      const int d = s * 3 + l;
      k_layer<<<256, 256, 0, stream>>>(hbuf[d & 1], wptr[l], bptr[l], xp, h32,
                                       hbuf[(d + 1) & 1]);
    }
  }
  k_head<<<128, 256, 0, stream>>>(hbuf[0], hw16, headb, (float*)d_out);
}

// Round 14
// 990.893 us; speedup vs baseline: 1.2675x; 1.2675x over previous
//
#include <hip/hip_runtime.h>
#include <hip/hip_fp16.h>
#include <math.h>

typedef _Float16 h16;
typedef __attribute__((ext_vector_type(8))) _Float16 half8;
typedef __attribute__((ext_vector_type(4))) float f32x4;

#define GLOAD_LDS16(gp, lp) __builtin_amdgcn_global_load_lds( \
    (const __attribute__((address_space(1))) void*)(gp),      \
    (__attribute__((address_space(3))) void*)(lp), 16, 0, 0)

// ---------------- 3-buffer GEMM core, XOR-swizzled LDS ----------------------
// LDS granule (row r, col-granule cg) holds global granule (r, cg ^ (r&7)).
// global_load_lds writes linearly (wave base + lane*16B) -> swizzle is applied
// on the per-lane GLOBAL source address; ds_read applies the same XOR (m201
// both-sides pattern, rule #21). Post-swizzle a quarter-wave's 16 lanes cover
// all 8 bank groups (2 lanes/bank = free, m136) instead of 16-way on one.
union SmemGemm3 {
  h16   buf[3][96 * 128];   // 3 x 24KB staging (A 32x128 | B 64x128)
  float red[4][2048];       // 32KB cross-wave reduction, aliased
};

__device__ __forceinline__ void stage3(SmemGemm3& sm, int bi,
                                       const h16* __restrict__ Ag,
                                       const h16* __restrict__ Bg,
                                       int kk, int kdim, int wave, int lane) {
  h16* As = sm.buf[bi];
  h16* Bs = As + 32 * 128;
  const int kb = kk * 128;
  // A tile: 32 rows x 128 k = 512 granules of 16B
#pragma unroll
  for (int i = 0; i < 2; ++i) {
    const int id = wave * 2 + i;              // 0..7
    const int chunk = id * 64 + lane;         // 0..511
    const int r = chunk >> 4, cg = chunk & 15;
    GLOAD_LDS16(Ag + (long)r * kdim + kb + ((cg ^ (r & 7)) << 3),
                As + id * 512);
  }
  // B tile: 64 rows x 128 k = 1024 granules
#pragma unroll
  for (int i = 0; i < 4; ++i) {
    const int id = wave * 4 + i;              // 0..15
    const int chunk = id * 64 + lane;         // 0..1023
    const int r = chunk >> 4, cg = chunk & 15;
    GLOAD_LDS16(Bg + (long)r * kdim + kb + ((cg ^ (r & 7)) << 3),
                Bs + id * 512);
  }
}

// C[i,j] partials in sm.red[wave][i*64+j]; caller sums the 4 waves.
// Wave w covers k-window [w*32, w*32+32) of each BK=128 slab.
// Depth-2 counted-vmcnt pipeline: 6 loads/wave/tile; steady-state vmcnt(12)
// keeps 2 tiles in flight across barriers (never drained to 0 mid-loop).
template <int KDIM>
__device__ __forceinline__ void gemm_core3(SmemGemm3& sm,
                                           const h16* __restrict__ Ag,
                                           const h16* __restrict__ Bg,
                                           int wave, int lane) {
  f32x4 acc[2][4];
#pragma unroll
  for (int a = 0; a < 2; ++a)
#pragma unroll
    for (int c = 0; c < 4; ++c) acc[a][c] = (f32x4){0.f, 0.f, 0.f, 0.f};

  const int mr = lane & 15, q = lane >> 4;
  const int kg = wave * 4 + q;                // k-granule 0..15
  const int ro = ((kg ^ (mr & 7)) << 3);      // swizzled elem offset in row
  constexpr int NIT = KDIM / 128;
  stage3(sm, 0, Ag, Bg, 0, KDIM, wave, lane);
  stage3(sm, 1, Ag, Bg, 1, KDIM, wave, lane);
#pragma unroll
  for (int kk = 0; kk < NIT; ++kk) {
    if (kk + 2 < NIT) {
      stage3(sm, (kk + 2) % 3, Ag, Bg, kk + 2, KDIM, wave, lane);
      asm volatile("s_waitcnt vmcnt(12)" ::: "memory");   // tile kk in LDS
    } else if (kk + 2 == NIT) {
      asm volatile("s_waitcnt vmcnt(6)" ::: "memory");
    } else {
      asm volatile("s_waitcnt vmcnt(0)" ::: "memory");
    }
    __builtin_amdgcn_s_barrier();
    const h16* As = sm.buf[kk % 3];
    const h16* Bs = As + 32 * 128;
    half8 a0 = *(const half8*)(As + mr * 128 + ro);
    half8 a1 = *(const half8*)(As + (mr + 16) * 128 + ro);   // (mr+16)&7 == mr&7
#pragma unroll
    for (int fc = 0; fc < 4; ++fc) {
      half8 bv = *(const half8*)(Bs + (fc * 16 + mr) * 128 + ro);
      acc[0][fc] = __builtin_amdgcn_mfma_f32_16x16x32_f16(a0, bv, acc[0][fc], 0, 0, 0);
      acc[1][fc] = __builtin_amdgcn_mfma_f32_16x16x32_f16(a1, bv, acc[1][fc], 0, 0, 0);
    }
    asm volatile("s_waitcnt lgkmcnt(0)" ::: "memory");      // my LDS reads done
    __builtin_amdgcn_s_barrier();
  }
  __syncthreads();                            // red aliases staging
#pragma unroll
  for (int fr = 0; fr < 2; ++fr)
#pragma unroll
    for (int fc = 0; fc < 4; ++fc)
#pragma unroll
      for (int r = 0; r < 4; ++r)
        sm.red[wave][(fr * 16 + q * 4 + r) * 64 + fc * 16 + mr] = acc[fr][fc][r];
  __syncthreads();
}

__device__ __forceinline__ float fast_tanh(float x) {
  float e = __expf(2.0f * fabsf(x));          // saturates safely for |x| large
  float t = 1.0f - 2.0f / (e + 1.0f);
  return copysignf(t, x);
}

// ---- pre-pass: sigma = ||W t|| / ||t||, t = W^T u --------------------------
__global__ void k_zero(float* tbuf, float* sbuf) {
  const int t = threadIdx.x;
  tbuf[t] = 0.f;
  if (t < 2) sbuf[t] = 0.f;
}

__global__ void __launch_bounds__(256)
k_prep1(const float* __restrict__ Win, const float* __restrict__ u,
        float* __restrict__ t) {
  const int kc = blockIdx.x & 3, jc = blockIdx.x >> 2;
  const int k = kc * 256 + threadIdx.x;       // coalesced
  const int j0 = jc * 64;
  float acc = 0.f;
#pragma unroll 4
  for (int j = 0; j < 64; ++j)
    acc = fmaf(Win[(long)(j0 + j) * 1024 + k], u[j0 + j], acc);
  atomicAdd(&t[k], acc);
}

__global__ void __launch_bounds__(256)
k_prep1b(const float* __restrict__ t, float* __restrict__ sbuf) {
  const int k = blockIdx.x * 256 + threadIdx.x;
  float v = t[k];
  float p = v * v;
#pragma unroll
  for (int off = 32; off > 0; off >>= 1) p += __shfl_down(p, off);
  if ((threadIdx.x & 63) == 0) atomicAdd(&sbuf[0], p);     // s1 = ||t||^2
}

__global__ void __launch_bounds__(256)
k_prep2(const float* __restrict__ Win, const float* __restrict__ t,
        float* __restrict__ sbuf) {
  const int row = blockIdx.x * 4 + (threadIdx.x >> 6);
  const int lane = threadIdx.x & 63;
  float acc = 0.f;
  for (int kk = lane; kk < 1024; kk += 64)
    acc = fmaf(Win[row * 1024 + kk], t[kk], acc);
#pragma unroll
  for (int off = 32; off > 0; off >>= 1) acc += __shfl_down(acc, off);
  if (lane == 0) atomicAdd(&sbuf[1], acc * acc);           // s2 = ||W t||^2
}

// ---- fp32 -> fp16 conversions (one fused elementwise pass) -----------------
__global__ void __launch_bounds__(256)
k_cvt(const float* __restrict__ W0, const float* __restrict__ W1,
      const float* __restrict__ W2, const float* __restrict__ Win,
      const float* __restrict__ Hw, const float* __restrict__ X,
      h16* __restrict__ w16, h16* __restrict__ wi16,
      h16* __restrict__ hw16, h16* __restrict__ x16) {
  const long e = (long)(blockIdx.x * 256 + threadIdx.x) * 8;
  const float* src; h16* dst;
  if (e < 4194304)       { src = W0 + e;              dst = w16 + e; }
  else if (e < 8388608)  { src = W1 + (e - 4194304);  dst = w16 + e; }
  else if (e < 12582912) { src = W2 + (e - 8388608);  dst = w16 + e; }
  else if (e < 14680064) { src = Win + (e - 12582912); dst = wi16 + (e - 12582912); }
  else if (e < 16728064) { src = Hw + (e - 14680064);  dst = hw16 + (e - 14680064); }
  else if (e < 16777216) {                              // zero-pad head_w rows 1000..1023
    half8 z = (half8){};
    *(half8*)(hw16 + 2048000 + (e - 16728064)) = z;
    return;
  }
  else                   { src = X + (e - 16777216);   dst = x16 + (e - 16777216); }
  f32x4 f0 = *(const f32x4*)src, f1 = *(const f32x4*)(src + 4);
  half8 h;
#pragma unroll
  for (int i = 0; i < 4; ++i) { h[i] = (h16)f0[i]; h[i + 4] = (h16)f1[i]; }
  *(half8*)dst = h;
}

// ---- x_proj = (x @ Win^T)/sigma + Win_b; zero h32/h16a ---------------------
__global__ void __launch_bounds__(256)
k_xproj(const h16* __restrict__ x16, const h16* __restrict__ wi16,
        const float* __restrict__ Winb, const float* __restrict__ sbuf,
        float* __restrict__ xp, float* __restrict__ h32, h16* __restrict__ h16a) {
  __shared__ SmemGemm3 sm;
  const int rb = blockIdx.x >> 5, cb = blockIdx.x & 31;
  const int wave = threadIdx.x >> 6, lane = threadIdx.x & 63;
  gemm_core3<1024>(sm, x16 + rb * 32 * 1024, wi16 + (long)cb * 64 * 1024, wave, lane);
  const float inv_sigma = sqrtf(sbuf[0] / sbuf[1]);        // ||t|| / ||W t||
  const int e = threadIdx.x * 8;
  const int gi = rb * 32 + (e >> 6), gj = cb * 64 + (e & 63);
  const long base = (long)gi * 2048 + gj;
  f32x4 s0 = *(const f32x4*)&sm.red[0][e], s1 = *(const f32x4*)&sm.red[0][e + 4];
#pragma unroll
  for (int w = 1; w < 4; ++w) {
    s0 += *(const f32x4*)&sm.red[w][e];
    s1 += *(const f32x4*)&sm.red[w][e + 4];
  }
  f32x4 b0v = *(const f32x4*)&Winb[gj], b1v = *(const f32x4*)&Winb[gj + 4];
  f32x4 v0 = s0 * inv_sigma + b0v, v1 = s1 * inv_sigma + b1v;
  *(f32x4*)&xp[base] = v0; *(f32x4*)&xp[base + 4] = v1;
  f32x4 zz = (f32x4){0.f, 0.f, 0.f, 0.f};
  *(f32x4*)&h32[base] = zz; *(f32x4*)&h32[base + 4] = zz;
  half8 hz = (half8){};
  *(half8*)&h16a[base] = hz;
}

// ---- one layer: h = 0.5h + 0.5 tanh(xp + h W^T + b) ------------------------
__global__ void __launch_bounds__(256)
k_layer(const h16* __restrict__ hin, const h16* __restrict__ W,
        const float* __restrict__ bl, const float* __restrict__ xp,
        float* __restrict__ h32, h16* __restrict__ hout) {
  __shared__ SmemGemm3 sm;
  const int rb = blockIdx.x >> 5, cb = blockIdx.x & 31;  // cb%8 == blk%8: XCD-pinned cols
  const int wave = threadIdx.x >> 6, lane = threadIdx.x & 63;
  gemm_core3<2048>(sm, hin + rb * 32 * 2048, W + (long)cb * 64 * 2048, wave, lane);
  const int e = threadIdx.x * 8;
  const int gi = rb * 32 + (e >> 6), gj = cb * 64 + (e & 63);
  const long base = (long)gi * 2048 + gj;
  f32x4 s0 = *(const f32x4*)&sm.red[0][e], s1 = *(const f32x4*)&sm.red[0][e + 4];
#pragma unroll
  for (int w = 1; w < 4; ++w) {
    s0 += *(const f32x4*)&sm.red[w][e];
    s1 += *(const f32x4*)&sm.red[w][e + 4];
  }
  f32x4 xp0 = *(const f32x4*)&xp[base], xp1 = *(const f32x4*)&xp[base + 4];
  f32x4 b0v = *(const f32x4*)&bl[gj],   b1v = *(const f32x4*)&bl[gj + 4];
  f32x4 ho0 = *(const f32x4*)&h32[base], ho1 = *(const f32x4*)&h32[base + 4];
  f32x4 z0 = xp0 + s0 + b0v, z1 = xp1 + s1 + b1v;
  f32x4 hn0, hn1; half8 hh;
#pragma unroll
  for (int i = 0; i < 4; ++i) {
    hn0[i] = 0.5f * ho0[i] + 0.5f * fast_tanh(z0[i]);
    hn1[i] = 0.5f * ho1[i] + 0.5f * fast_tanh(z1[i]);
    hh[i] = (h16)hn0[i]; hh[i + 4] = (h16)hn1[i];
  }
  *(f32x4*)&h32[base] = hn0; *(f32x4*)&h32[base + 4] = hn1;
  *(half8*)&hout[base] = hh;
}

// ---- head: out = h @ head_w^T + head_b -------------------------------------
__global__ void __launch_bounds__(256)
k_head(const h16* __restrict__ hf, const h16* __restrict__ hw16,
       const float* __restrict__ hb, float* __restrict__ out) {
  __shared__ SmemGemm3 sm;
  const int rb = blockIdx.x >> 4, cb = blockIdx.x & 15;
  const int wave = threadIdx.x >> 6, lane = threadIdx.x & 63;
  gemm_core3<2048>(sm, hf + rb * 32 * 2048, hw16 + (long)cb * 64 * 2048, wave, lane);
  const int e = threadIdx.x * 8;
  const int gi = rb * 32 + (e >> 6), gj = cb * 64 + (e & 63);
  f32x4 s0 = *(const f32x4*)&sm.red[0][e], s1 = *(const f32x4*)&sm.red[0][e + 4];
#pragma unroll
  for (int w = 1; w < 4; ++w) {
    s0 += *(const f32x4*)&sm.red[w][e];
    s1 += *(const f32x4*)&sm.red[w][e + 4];
  }
#pragma unroll
  for (int i = 0; i < 4; ++i) {
    int j0 = gj + i;
    if (j0 < 1000) out[(long)gi * 1000 + j0] = s0[i] + hb[j0];
    int j1 = gj + 4 + i;
    if (j1 < 1000) out[(long)gi * 1000 + j1] = s1[i] + hb[j1];
  }
}

// ---- workspace layout (bytes) ----------------------------------------------
#define OFF_W16   0L          // 3 x 2048x2048 fp16 = 25165824
#define OFF_WI16  25165824L   // 2048x1024 fp16     =  4194304
#define OFF_X16   29360128L   // 256x1024 fp16      =   524288
#define OFF_HW16  29884416L   // 1024x2048 fp16     =  4194304 (padded rows)
#define OFF_XP    34078720L   // 256x2048 fp32      =  2097152
#define OFF_H32   36175872L   // 256x2048 fp32      =  2097152
#define OFF_H16A  38273024L   // 256x2048 fp16      =  1048576
#define OFF_H16B  39321600L   //                    =  1048576
#define OFF_T     40370176L   // 1024 fp32
#define OFF_S     40374272L   // s1, s2

extern "C" void kernel_launch(void* const* d_in, const int* in_sizes, int n_in,
                              void* d_out, int out_size, void* d_ws, size_t ws_size,
                              hipStream_t stream) {
  const float* x     = (const float*)d_in[0];
  const float* Win_w = (const float*)d_in[1];
  const float* Win_b = (const float*)d_in[2];
  const float* u     = (const float*)d_in[3];
  const float* W0    = (const float*)d_in[4];
  const float* b0    = (const float*)d_in[5];
  const float* W1    = (const float*)d_in[6];
  const float* b1    = (const float*)d_in[7];
  const float* W2    = (const float*)d_in[8];
  const float* b2    = (const float*)d_in[9];
  const float* headw = (const float*)d_in[10];
  const float* headb = (const float*)d_in[11];

  char* ws = (char*)d_ws;
  h16*   w16  = (h16*)(ws + OFF_W16);
  h16*   wi16 = (h16*)(ws + OFF_WI16);
  h16*   x16  = (h16*)(ws + OFF_X16);
  h16*   hw16 = (h16*)(ws + OFF_HW16);
  float* xp   = (float*)(ws + OFF_XP);
  float* h32  = (float*)(ws + OFF_H32);
  h16*   h16a = (h16*)(ws + OFF_H16A);
  h16*   h16b = (h16*)(ws + OFF_H16B);
  float* tbuf = (float*)(ws + OFF_T);
  float* sbuf = (float*)(ws + OFF_S);

  k_zero<<<1, 1024, 0, stream>>>(tbuf, sbuf);
  k_prep1<<<128, 256, 0, stream>>>(Win_w, u, tbuf);
  k_prep1b<<<4, 256, 0, stream>>>(tbuf, sbuf);
  k_prep2<<<512, 256, 0, stream>>>(Win_w, tbuf, sbuf);
  k_cvt<<<8320, 256, 0, stream>>>(W0, W1, W2, Win_w, headw, x, w16, wi16, hw16, x16);
  k_xproj<<<256, 256, 0, stream>>>(x16, wi16, Win_b, sbuf, xp, h32, h16a);

  const h16*   wptr[3] = {w16, w16 + 4194304, w16 + 8388608};
  const float* bptr[3] = {b0, b1, b2};
  h16* hbuf[2] = {h16a, h16b};
  for (int s = 0; s < 30; ++s) {
    for (int l = 0; l < 3; ++l) {
      const int d = s * 3 + l;
      k_layer<<<256, 256, 0, stream>>>(hbuf[d & 1], wptr[l], bptr[l], xp, h32,
                                       hbuf[(d + 1) & 1]);
    }
  }
  k_head<<<128, 256, 0, stream>>>(hbuf[0], hw16, headb, (float*)d_out);
}